// Round 5
// baseline (589.820 us; speedup 1.0000x reference)
//
#include <hip/hip_runtime.h>
#include <hip/hip_bf16.h>

// Problem constants (GATModule: N=8192, IN=128, OUT=64, H=4) — fp32 inputs/output.
#define NN   8192
#define IND  128
#define OUTD 64
#define NH   4
#define NEG_SLOPE 0.2f
#define BN_EPS 1e-5f

typedef __attribute__((ext_vector_type(8))) short bf16x8;   // MFMA A/B frag (8 bf16, guide-verified typing)
typedef __attribute__((ext_vector_type(4))) float f32x4;    // MFMA C/D frag
typedef __attribute__((ext_vector_type(4))) int   i32x4;

static __device__ __forceinline__ float bf2f(short s) {
    union { unsigned u; float f; } v; v.u = ((unsigned)(unsigned short)s) << 16; return v.f;
}
static __device__ __forceinline__ short f2bf(float f) {
    union { float f; unsigned u; } v; v.f = f;
    return (short)((v.u + 0x8000u) >> 16);
}

// ---------------- Canonical-name kernel (canary; launched FIRST, K5 overwrites) ------------
__global__ void GATModule_7636451852431_kernel(float* out) {
    out[0] = 1000.0f;
}

// ---------------- K0: repack W[h][k][o] fp32 -> WB bf16 [h][k/8][o][k%8] (B-frag) ----------
__global__ __launch_bounds__(256) void k0_repackW(const float* __restrict__ W,
                                                  short* __restrict__ WB) {
    int tid = blockIdx.x * 256 + threadIdx.x;      // 0..32767
    int o = tid & 63, i = (tid >> 6) & 127, h = tid >> 13;
    WB[((h * 16 + (i >> 3)) * 64 + o) * 8 + (i & 7)] = f2bf(W[(h * 128 + i) * 64 + o]);
}

// ---------------- K1: h = x@W per head (MFMA); store hB bf16 + exp tables ------------------
// grid 512 (16 rows each), block 256 (wave w = head w)
__global__ __launch_bounds__(256) void k1_feat(const float* __restrict__ x,
                                               const short* __restrict__ WB,
                                               const float* __restrict__ a_i,
                                               const float* __restrict__ a_j,
                                               short* __restrict__ hB,
                                               float* __restrict__ t_ei,  float* __restrict__ t_E1i,
                                               float* __restrict__ t_E2i, float* __restrict__ t_nj,
                                               float* __restrict__ t_E1j, float* __restrict__ t_E2j) {
    int w = threadIdx.x >> 6;        // head
    int l = threadIdx.x & 63;
    int quad = l >> 4, lx = l & 15;
    int rb = blockIdx.x;             // 16-row block

    f32x4 acc[4] = {};               // 4 o-tiles of 16
#pragma unroll
    for (int ks = 0; ks < 4; ++ks) { // K=128 in 4 steps of 32
        const float* xp = x + (rb * 16 + lx) * IND + ks * 32 + quad * 8;
        f32x4 xa = *(const f32x4*)xp;
        f32x4 xb = *(const f32x4*)(xp + 4);
        bf16x8 af;
#pragma unroll
        for (int j = 0; j < 4; ++j) { af[j] = f2bf(xa[j]); af[4 + j] = f2bf(xb[j]); }
#pragma unroll
        for (int ot = 0; ot < 4; ++ot) {
            bf16x8 bf = *(const bf16x8*)(WB + ((w * 16 + ks * 4 + quad) * 64 + ot * 16 + lx) * 8);
            acc[ot] = __builtin_amdgcn_mfma_f32_16x16x32_bf16(af, bf, acc[ot], 0, 0, 0);
        }
    }
    float aiv[4], ajv[4];
#pragma unroll
    for (int ot = 0; ot < 4; ++ot) {
        aiv[ot] = a_i[w * 64 + ot * 16 + lx];
        ajv[ot] = a_j[w * 64 + ot * 16 + lx];
    }
#pragma unroll
    for (int reg = 0; reg < 4; ++reg) {
        int row = rb * 16 + quad * 4 + reg;       // C-layout: row=quad*4+reg, col=lane&15
        float ei = 0.f, ej = 0.f;
#pragma unroll
        for (int ot = 0; ot < 4; ++ot) {
            float hv = acc[ot][reg];
            ei += hv * aiv[ot];
            ej += hv * ajv[ot];
        }
#pragma unroll
        for (int m = 1; m <= 8; m <<= 1) {        // reduce over the 16 lanes of this row
            ei += __shfl_xor(ei, m, 64);
            ej += __shfl_xor(ej, m, 64);
        }
        if (lx == reg) {
            t_ei [w * NN + row] = ei;
            t_E1i[w * NN + row] = expf(ei);
            t_E2i[w * NN + row] = expf(NEG_SLOPE * ei);
            t_nj [w * NN + row] = -ej;
            t_E1j[w * NN + row] = expf(ej);
            t_E2j[w * NN + row] = expf(NEG_SLOPE * ej);
        }
#pragma unroll
        for (int ot = 0; ot < 4; ++ot) {          // hB[h][n/8][o][n%8]
            int o = ot * 16 + lx;
            hB[((w * 1024 + (row >> 3)) * 64 + o) * 8 + (row & 7)] = f2bf(acc[ot][reg]);
        }
    }
}

// ---------------- K2: main attention kernel ------------------------------------------------
// grid 512 = 128 rowblocks(64) x 4 K-splits(2048 cols); block 256 = 4 waves, wave w = head w
__global__ __launch_bounds__(256) void k2_attn(const int* __restrict__ adj,
                                               const short* __restrict__ hB,
                                               const float* __restrict__ t_ei,
                                               const float* __restrict__ t_E1i,
                                               const float* __restrict__ t_E2i,
                                               const float* __restrict__ t_nj,
                                               const float* __restrict__ t_E1j,
                                               const float* __restrict__ t_E2j,
                                               float* __restrict__ num,
                                               float* __restrict__ Lsum) {
    int w = threadIdx.x >> 6;                  // head
    int l = threadIdx.x & 63;
    int quad = l >> 4, lx = l & 15;
    int rb = blockIdx.x >> 2, ks = blockIdx.x & 3;
    int rowbase = rb * 64;
    int tb = w * NN;

    float eiv[4], E1i[4], E2i[4];
#pragma unroll
    for (int r = 0; r < 4; ++r) {
        int i = rowbase + r * 16 + lx;         // A row: lane&15
        eiv[r] = t_ei[tb + i];
        E1i[r] = t_E1i[tb + i];
        E2i[r] = t_E2i[tb + i];
    }

    f32x4 acc[4][4] = {};                      // [m-tile][o-tile]
    float Lacc[4] = {0.f, 0.f, 0.f, 0.f};
    int k0 = ks * 2048;

#pragma unroll 1
    for (int kt = 0; kt < 64; ++kt) {
        int kb = k0 + kt * 32 + quad * 8;      // this lane's 8-wide k slice
        f32x4 nj0  = *(const f32x4*)(t_nj  + tb + kb);
        f32x4 nj1  = *(const f32x4*)(t_nj  + tb + kb + 4);
        f32x4 e1j0 = *(const f32x4*)(t_E1j + tb + kb);
        f32x4 e1j1 = *(const f32x4*)(t_E1j + tb + kb + 4);
        f32x4 e2j0 = *(const f32x4*)(t_E2j + tb + kb);
        f32x4 e2j1 = *(const f32x4*)(t_E2j + tb + kb + 4);

        bf16x8 bfrag[4];
#pragma unroll
        for (int ot = 0; ot < 4; ++ot)         // B-frag: one 16B load
            bfrag[ot] = *(const bf16x8*)(hB + ((w * 1024 + (kb >> 3)) * 64 + ot * 16 + lx) * 8);

        bf16x8 afr[4];
#pragma unroll
        for (int r = 0; r < 4; ++r) {
            const int* ap = adj + (size_t)(rowbase + r * 16 + lx) * NN + kb;
            i32x4 a0 = *(const i32x4*)ap;
            i32x4 a1 = *(const i32x4*)(ap + 4);
            bf16x8 af;
            float lsum = 0.f;
#pragma unroll
            for (int j = 0; j < 8; ++j) {
                int   av = (j < 4) ? a0[j] : a1[j - 4];
                float nj = (j < 4) ? nj0[j] : nj1[j - 4];
                float e1 = (j < 4) ? e1j0[j] : e1j1[j - 4];
                float e2 = (j < 4) ? e2j0[j] : e2j1[j - 4];
                bool  c  = eiv[r] >= nj;       // s = ei+ej >= 0
                float p  = (c ? E1i[r] : E2i[r]) * (c ? e1 : e2);
                p = av ? p : 0.0f;             // adjacency mask
                short ps = f2bf(p);
                af[j] = ps;
                lsum += bf2f(ps);              // denominator = sum of the values MFMA actually uses
            }
            Lacc[r] += lsum;
            afr[r] = af;
        }
#pragma unroll
        for (int r = 0; r < 4; ++r)
#pragma unroll
            for (int ot = 0; ot < 4; ++ot)
                acc[r][ot] = __builtin_amdgcn_mfma_f32_16x16x32_bf16(afr[r], bfrag[ot], acc[r][ot], 0, 0, 0);
    }

    // softmax denominators: combine the 4 k-quads (lanes x, x^16, x^32)
#pragma unroll
    for (int r = 0; r < 4; ++r) {
        float L = Lacc[r];
        L += __shfl_xor(L, 16, 64);
        L += __shfl_xor(L, 32, 64);
        if (l < 16)
            atomicAdd(&Lsum[w * NN + rowbase + r * 16 + lx], L);
    }
    // numerator: atomic combine across the 4 K-splits
#pragma unroll
    for (int r = 0; r < 4; ++r)
#pragma unroll
        for (int ot = 0; ot < 4; ++ot)
#pragma unroll
            for (int reg = 0; reg < 4; ++reg) {
                int row = rowbase + r * 16 + quad * 4 + reg;    // C/D: row=quad*4+reg
                atomicAdd(&num[row * 256 + w * 64 + ot * 16 + lx], acc[r][ot][reg]);
            }
}

// ---------------- K3: divide by L in-place, BN partial stats -------------------------------
// grid 256 blocks x 32 rows; thread t = column c (h*64+o)
__global__ __launch_bounds__(256) void k3_combine(float* __restrict__ num,
                                                  const float* __restrict__ Lsum,
                                                  float* __restrict__ stats) {
    int c = threadIdx.x;
    int h = c >> 6;
    float s = 0.f, s2 = 0.f;
    for (int rr = 0; rr < 32; ++rr) {
        int row = blockIdx.x * 32 + rr;
        float L = Lsum[h * NN + row];
        float val = num[row * 256 + c] / L;
        num[row * 256 + c] = val;              // in-place: becomes preout
        s += val; s2 += val * val;
    }
    atomicAdd(&stats[c], s);
    atomicAdd(&stats[c + 256], s2);
}

// ---------------- K4: finalize BN scale/shift (fp32 gamma/beta) ----------------------------
__global__ __launch_bounds__(256) void k4_bnfinal(const float* __restrict__ stats,
                                                  const float* __restrict__ gamma,
                                                  const float* __restrict__ beta,
                                                  float* __restrict__ bnp) {
    int c = threadIdx.x;
    float mean = stats[c] * (1.0f / NN);
    float var  = stats[c + 256] * (1.0f / NN) - mean * mean;
    float sc = gamma[c] * rsqrtf(var + BN_EPS);
    bnp[c] = sc;
    bnp[c + 256] = beta[c] - mean * sc;
}

// ---------------- K5: apply BN + ReLU -> fp32 out (NaN visible, stage sentinels) -----------
__global__ __launch_bounds__(256) void k5_apply(const float* __restrict__ preout,
                                                const float* __restrict__ bnp,
                                                const short* __restrict__ hB,
                                                const float* __restrict__ Lsum,
                                                float* __restrict__ out) {
    int g = blockIdx.x * 256 + threadIdx.x;        // float4 index, 524288 total
    f32x4 v = *(const f32x4*)(preout + (size_t)g * 4);
    int cb = (g * 4) & 255;
    f32x4 r;
#pragma unroll
    for (int j = 0; j < 4; ++j) {
        float y = v[j] * bnp[cb + j] + bnp[256 + cb + j];
        if (!(y == y)) y = 54321.0f;               // NaN -> visible sentinel, never laundered
        else y = fmaxf(y, 0.0f);
        r[j] = y;
    }
    // Stage sentinels (one thread; healthy runs untouched):
    if (g == 0) {
        float sh = 0.f;
        for (int j = 0; j < 8; ++j) sh += fabsf(bf2f(hB[j]));       // h features row 0..7, o=0
        float sl = Lsum[0];                                          // denominator head0 row0
        float sp = 0.f;
        for (int rr = 0; rr < 4; ++rr) {                             // sample 4 spread rows
            const float* pr = preout + (size_t)(rr * 2111) * 256;
            for (int c = 0; c < 256; ++c) sp += fabsf(pr[c]);
        }
        float sentinel = 0.f;
        if (!(sh > 1e-6f))      sentinel = 30000.f;  // K0/K1 dead (h == 0)
        else if (!(sl > 1.0f))  sentinel = 40000.f;  // K2 denominator dead
        else if (!(sp > 1e-6f)) sentinel = 20000.f;  // K2 numerator / K3 dead
        else if (!(sp == sp))   sentinel = 50000.f;  // NaN already in preout
        if (sentinel != 0.f) r[0] = sentinel;
    }
    *(f32x4*)(out + (size_t)g * 4) = r;
}

extern "C" void kernel_launch(void* const* d_in, const int* in_sizes, int n_in,
                              void* d_out, int out_size, void* d_ws, size_t ws_size,
                              hipStream_t stream) {
    (void)in_sizes; (void)n_in; (void)out_size; (void)ws_size;
    const float* x     = (const float*)d_in[0];
    const int*   adj   = (const int*)d_in[1];
    const float* W     = (const float*)d_in[2];
    const float* a_i   = (const float*)d_in[3];
    const float* a_j   = (const float*)d_in[4];
    const float* gamma = (const float*)d_in[5];
    const float* beta  = (const float*)d_in[6];
    float* out = (float*)d_out;

    char* ws = (char*)d_ws;
    // workspace layout (~13.6 MB total)
    short* WB    = (short*)(ws + 0);              //   64 KB (bf16 W, B-frag layout)
    short* hB    = (short*)(ws + 65536);          //    4 MB (bf16 h, B-frag layout)
    float* t_ei  = (float*)(ws + 4259840);        // 6 x 128 KB tables
    float* t_E1i = t_ei + 32768;
    float* t_E2i = t_ei + 2 * 32768;
    float* t_nj  = t_ei + 3 * 32768;
    float* t_E1j = t_ei + 4 * 32768;
    float* t_E2j = t_ei + 5 * 32768;
    float* num   = (float*)(ws + 5046272);        //    8 MB (numerator -> preout in-place)
    float* Lsum  = (float*)(ws + 13434880);       //  128 KB
    float* stats = (float*)(ws + 13565952);       //    2 KB (atomic accum)
    float* bnp   = (float*)(ws + 13568000);       //    2 KB

    hipMemsetAsync(num,   0, 8388608, stream);
    hipMemsetAsync(Lsum,  0, 131072, stream);
    hipMemsetAsync(stats, 0, 2048, stream);

    GATModule_7636451852431_kernel<<<dim3(1), dim3(1), 0, stream>>>(out);  // canary
    k0_repackW<<<dim3(128), dim3(256), 0, stream>>>(W, WB);
    k1_feat   <<<dim3(512), dim3(256), 0, stream>>>(x, WB, a_i, a_j, hB,
                                                    t_ei, t_E1i, t_E2i, t_nj, t_E1j, t_E2j);
    k2_attn   <<<dim3(512), dim3(256), 0, stream>>>(adj, hB, t_ei, t_E1i, t_E2i,
                                                    t_nj, t_E1j, t_E2j, num, Lsum);
    k3_combine<<<dim3(256), dim3(256), 0, stream>>>(num, Lsum, stats);
    k4_bnfinal<<<dim3(1),   dim3(256), 0, stream>>>(stats, gamma, beta, bnp);
    k5_apply  <<<dim3(2048), dim3(256), 0, stream>>>(num, bnp, hB, Lsum, out);
}